// Round 3
// baseline (2310.126 us; speedup 1.0000x reference)
//
#include <hip/hip_runtime.h>
#include <math.h>

#define NB   256
#define LSEQ 1800
#define NF   50
#define NE   4
#define NH   32
#define G3   96
#define ND   64
#define NHU  32
#define CHUNK 72
#define TBLK  8
#define NCHUNK (LSEQ / CHUNK)   // 25
#define NBLK   (CHUNK / TBLK)   // 9

typedef float v2f __attribute__((ext_vector_type(2)));

__device__ __forceinline__ v2f v2fma(v2f a, v2f b, v2f c) {
    return __builtin_elementwise_fma(a, b, c);
}
__device__ __forceinline__ v2f mkv2(float a, float b) { v2f t; t.x = a; t.y = b; return t; }
__device__ __forceinline__ v2f splat2(float s) { v2f t; t.x = s; t.y = s; return t; }

// ---------------------------------------------------------------------------
// Kernel 1: fold input projection into layer-0 input weights.
// Cg[e][f][g] = sum_d Wih0[e][g][d] * W_in[d][f]
// ---------------------------------------------------------------------------
__global__ void compute_C_kernel(const float* __restrict__ Wih0,
                                 const float* __restrict__ W_in,
                                 float* __restrict__ Cg) {
    int e = blockIdx.x;
    for (int idx = threadIdx.x; idx < NF * G3; idx += blockDim.x) {
        int f = idx / G3;
        int g = idx - f * G3;
        const float* wr = Wih0 + ((size_t)e * G3 + g) * ND;
        float s = 0.f;
        #pragma unroll 8
        for (int d = 0; d < ND; d++) s += wr[d] * W_in[d * NF + f];
        Cg[(size_t)e * NF * G3 + idx] = s;
    }
}

// ---------------------------------------------------------------------------
// Kernel 2: routing.  One block, 256 threads; thread t = batch t.  Computes
// top-2 gating (identical tie-break to jax.lax.top_k: first max wins) and
// appends (batch, weight) to each chosen expert's compacted list.  Slot order
// is irrelevant: the main kernel accumulates via atomicAdd.
// ---------------------------------------------------------------------------
__global__ void routing_kernel(const int*   __restrict__ horizon,
                               const float* __restrict__ emb,
                               const float* __restrict__ W_gate,
                               const float* __restrict__ b_gate,
                               int* __restrict__ lst, float* __restrict__ wl,
                               int* __restrict__ cnt) {
    __shared__ int scnt[NE];
    const int t = threadIdx.x;
    if (t < NE) scnt[t] = 0;
    __syncthreads();
    int hor = horizon[t];
    const float* he = emb + (size_t)hor * ND;
    float lg[NE];
    #pragma unroll
    for (int q = 0; q < NE; q++) {
        float s = b_gate[q];
        for (int d = 0; d < ND; d++) s += he[d] * W_gate[q * ND + d];
        lg[q] = s;
    }
    int i1 = 0;
    #pragma unroll
    for (int q = 1; q < NE; q++) if (lg[q] > lg[i1]) i1 = q;
    int i2 = (i1 == 0) ? 1 : 0;
    #pragma unroll
    for (int q = 0; q < NE; q++) if (q != i1 && lg[q] > lg[i2]) i2 = q;
    float ex2 = expf(lg[i2] - lg[i1]);
    float w1 = 1.f / (1.f + ex2);
    float w2 = ex2 / (1.f + ex2);
    int s1 = atomicAdd(&scnt[i1], 1);
    lst[i1 * NB + s1] = t;  wl[i1 * NB + s1] = w1;
    int s2 = atomicAdd(&scnt[i2], 1);
    lst[i2 * NB + s2] = t;  wl[i2 * NB + s2] = w2;
    __syncthreads();
    if (t < NE) cnt[t] = scnt[t];
}

// Fast transcendentals on v_exp_f32 / v_rcp_f32.
__device__ __forceinline__ float fsig(float x) {
    float e = __builtin_amdgcn_exp2f(-1.442695041f * x);
    return __builtin_amdgcn_rcpf(1.f + e);
}
__device__ __forceinline__ float ftanh(float x) {
    x = fmaxf(x, -20.f);
    float e = __builtin_amdgcn_exp2f(-2.885390082f * x);
    return (1.f - e) * __builtin_amdgcn_rcpf(1.f + e);
}

// ---------------------------------------------------------------------------
// One 64-thread (single-wave) block per PAIR of routed batches of the same
// expert.  The wave is latency-bound (1 wave/SIMD, ~25% VALUBusy): two
// independent GRU chains interleaved in one wave fill each other's dependence
// stalls (ILP where TLP is impossible without spilling).  Weights (sA/wB) and
// the CT tile are shared across the pair; per-batch state is duplicated.
// Role split per batch as before: half0 lane j = L0(t) row j; half1 lane j =
// L1(t-1) row j; h0 broadcast via v_readlane, h1 via LDS; no barriers.
// ---------------------------------------------------------------------------
__global__ __launch_bounds__(64, 1)
void moe_gru_kernel(const float* __restrict__ x,
                    const int*   __restrict__ horizon,
                    const float* __restrict__ emb,
                    const float* __restrict__ b_in,
                    const float* __restrict__ Wih0,
                    const float* __restrict__ Whh0,
                    const float* __restrict__ bih0,
                    const float* __restrict__ bhh0,
                    const float* __restrict__ Wih1,
                    const float* __restrict__ Whh1,
                    const float* __restrict__ bih1,
                    const float* __restrict__ bhh1,
                    const float* __restrict__ Wh1,
                    const float* __restrict__ bh1,
                    const float* __restrict__ Wh2,
                    const float* __restrict__ bh2,
                    const float* __restrict__ Cg,
                    const int*   __restrict__ lst,
                    const float* __restrict__ wl,
                    const int*   __restrict__ cnt,
                    float* __restrict__ out) {
    __shared__ __align__(16) float smem[4800 + 2 * 3600 + 2 * 64 + 2 * 32];
    float* CT  = smem;                  // [f][96] folded xg0 weights (shared)
    float* xsA = smem + 4800;           // [f][CHUNK] batch-A x chunk
    float* xsB = smem + 8400;           // [f][CHUNK] batch-B x chunk
    float* bbA = smem + 12000;          // 64: b_in + h_embed (A)
    float* bbB = smem + 12064;          // 64: b_in + h_embed (B)
    float* h1A = smem + 12128;          // 32: h1 exchange (A)
    float* h1B = smem + 12160;          // 32: h1 exchange (B)

    const int e   = blockIdx.x;
    const int p   = blockIdx.y;
    const int tid = threadIdx.x;
    const int j   = tid & 31;
    const int hlf = tid >> 5;
    const int k0h = hlf << 4;

    const int c  = cnt[e];
    const int s0 = 2 * p;
    if (s0 >= c) return;                       // block-uniform
    const int   bA   = lst[e * NB + s0];
    const float wgtA = wl[e * NB + s0];
    const bool  hasB = (s0 + 1) < c;
    const int   bB   = hasB ? lst[e * NB + s0 + 1] : bA;
    const float wgtB = hasB ? wl[e * NB + s0 + 1] : 0.f;

    // ---- stage folded xg0 weights (shared) ----
    for (int idx = tid; idx < NF * G3; idx += 64)
        CT[idx] = Cg[(size_t)e * NF * G3 + idx];

    // ---- stage b_in + h_embed per batch (wave-synchronous) ----
    bbA[tid] = emb[(size_t)horizon[bA] * ND + tid] + b_in[tid];
    bbB[tid] = emb[(size_t)horizon[bB] * ND + tid] + b_in[tid];

    // ---- per-lane weights (shared across the pair) ----
    // selA: half0 -> Whh0 rows {j, j+32, j+64}; half1 -> Wih1 rows (full 32-k)
    v2f sA0[16], sA1[16], sA2[16];
    // wB: Whh1 rows {j, j+32, j+64}, k-half [k0h, k0h+16)
    v2f wB0[8], wB1[8], wB2[8];
    {
        const float* baseA = (hlf ? Wih1 : Whh0) + (size_t)e * G3 * NH;
        const float* rA0 = baseA + (size_t)j * NH;
        const float* rA1 = baseA + (size_t)(j + 32) * NH;
        const float* rA2 = baseA + (size_t)(j + 64) * NH;
        #pragma unroll
        for (int q4 = 0; q4 < 8; q4++) {
            float4 qa = ((const float4*)rA0)[q4];
            sA0[2*q4] = mkv2(qa.x, qa.y); sA0[2*q4+1] = mkv2(qa.z, qa.w);
            float4 qb = ((const float4*)rA1)[q4];
            sA1[2*q4] = mkv2(qb.x, qb.y); sA1[2*q4+1] = mkv2(qb.z, qb.w);
            float4 qc = ((const float4*)rA2)[q4];
            sA2[2*q4] = mkv2(qc.x, qc.y); sA2[2*q4+1] = mkv2(qc.z, qc.w);
        }
        const float* baseB = Whh1 + (size_t)e * G3 * NH;
        const float* rB0 = baseB + (size_t)j * NH + k0h;
        const float* rB1 = baseB + (size_t)(j + 32) * NH + k0h;
        const float* rB2 = baseB + (size_t)(j + 64) * NH + k0h;
        #pragma unroll
        for (int q4 = 0; q4 < 4; q4++) {
            float4 qa = ((const float4*)rB0)[q4];
            wB0[2*q4] = mkv2(qa.x, qa.y); wB0[2*q4+1] = mkv2(qa.z, qa.w);
            float4 qb = ((const float4*)rB1)[q4];
            wB1[2*q4] = mkv2(qb.x, qb.y); wB1[2*q4+1] = mkv2(qb.z, qb.w);
            float4 qc = ((const float4*)rB2)[q4];
            wB2[2*q4] = mkv2(qc.x, qc.y); wB2[2*q4+1] = mkv2(qc.z, qc.w);
        }
    }
    const float selb0 = hlf ? bih1[e*G3 + j]      : bhh0[e*G3 + j];
    const float selb1 = hlf ? bih1[e*G3 + j + 32] : bhh0[e*G3 + j + 32];
    const float selb2 = hlf ? bih1[e*G3 + j + 64] : bhh0[e*G3 + j + 64];
    const float whb0  = hlf ? 0.f : bhh1[e*G3 + j];
    const float whb1  = hlf ? 0.f : bhh1[e*G3 + j + 32];
    const float whb2  = hlf ? 0.f : bhh1[e*G3 + j + 64];

    // dreg = bih0 + Wih0 @ (b_in + h_embed), per batch
    float dregA0, dregA1, dregA2, dregB0, dregB1, dregB2;
    {
        const float* w0 = Wih0 + ((size_t)e * G3 + j) * ND;
        const float* w1 = Wih0 + ((size_t)e * G3 + j + 32) * ND;
        const float* w2 = Wih0 + ((size_t)e * G3 + j + 64) * ND;
        float a0 = bih0[e*G3 + j], a1 = bih0[e*G3 + j + 32], a2 = bih0[e*G3 + j + 64];
        float b0 = a0, b1 = a1, b2 = a2;
        for (int d = 0; d < ND; d++) {
            float wv0 = w0[d], wv1 = w1[d], wv2 = w2[d];
            float xa = bbA[d], xb = bbB[d];
            a0 += wv0 * xa; a1 += wv1 * xa; a2 += wv2 * xa;
            b0 += wv0 * xb; b1 += wv1 * xb; b2 += wv2 * xb;
        }
        dregA0 = hlf ? 0.f : a0; dregA1 = hlf ? 0.f : a1; dregA2 = hlf ? 0.f : a2;
        dregB0 = hlf ? 0.f : b0; dregB1 = hlf ? 0.f : b1; dregB2 = hlf ? 0.f : b2;
    }

    // ---- pipeline state (per batch) ----
    v2f h0vA[16], h0vB[16], h1vA[8], h1vB[8];
    #pragma unroll
    for (int k = 0; k < 16; k++) { h0vA[k] = splat2(0.f); h0vB[k] = splat2(0.f); }
    #pragma unroll
    for (int k = 0; k < 8; k++)  { h1vA[k] = splat2(0.f); h1vB[k] = splat2(0.f); }
    float holdA = 0.f, holdB = 0.f;
    float lmul = hlf ? 0.f : 1.f;        // neutralizes the fake first L1 step
    if (tid < 32) { h1A[tid] = 0.f; h1B[tid] = 0.f; }

    const float* xgA = x + (size_t)bA * LSEQ * NF;
    const float* xgB = x + (size_t)bB * LSEQ * NF;

    for (int ch = 0; ch < NCHUNK; ch++) {
        // stage both x chunks (contiguous float4 loads), transpose to [f][t]
        {
            const float4* xa4 = (const float4*)(xgA + (size_t)ch * CHUNK * NF);
            const float4* xb4 = (const float4*)(xgB + (size_t)ch * CHUNK * NF);
            for (int i4 = tid; i4 < (CHUNK * NF) / 4; i4 += 64) {
                float4 va = xa4[i4];
                float4 vb = xb4[i4];
                int idx = i4 * 4;
                #pragma unroll
                for (int u = 0; u < 4; u++) {
                    int id = idx + u;
                    int it = (int)(((unsigned)id * 5243u) >> 18);   // id/50
                    int f  = id - it * 50;
                    float fa = (u == 0) ? va.x : (u == 1) ? va.y : (u == 2) ? va.z : va.w;
                    float fb = (u == 0) ? vb.x : (u == 1) ? vb.y : (u == 2) ? vb.z : vb.w;
                    xsA[f * CHUNK + it] = fa;
                    xsB[f * CHUNK + it] = fb;
                }
            }
        }

        for (int blk = 0; blk < NBLK; blk++) {
            const int ib0 = blk * TBLK;
            // ---- xg0 partials for TBLK steps, both batches (f-split) ----
            v2f aA0[4], aA1[4], aA2[4], aB0[4], aB1[4], aB2[4];
            #pragma unroll
            for (int q = 0; q < 4; q++) {
                aA0[q] = splat2(dregA0); aA1[q] = splat2(dregA1); aA2[q] = splat2(dregA2);
                aB0[q] = splat2(dregB0); aB1[q] = splat2(dregB1); aB2[q] = splat2(dregB2);
            }
            {
                const int fb = 25 * hlf;
                #pragma unroll 5
                for (int f = 0; f < 25; f++) {
                    const int fg = fb + f;
                    float c0 = CT[fg * G3 + j];
                    float c1 = CT[fg * G3 + j + 32];
                    float c2 = CT[fg * G3 + j + 64];
                    const float4* xpA = (const float4*)(xsA + fg * CHUNK + ib0);
                    float4 xa = xpA[0], xb = xpA[1];
                    v2f xvA[4] = { mkv2(xa.x, xa.y), mkv2(xa.z, xa.w),
                                   mkv2(xb.x, xb.y), mkv2(xb.z, xb.w) };
                    const float4* xpB = (const float4*)(xsB + fg * CHUNK + ib0);
                    float4 ya = xpB[0], yb = xpB[1];
                    v2f xvB[4] = { mkv2(ya.x, ya.y), mkv2(ya.z, ya.w),
                                   mkv2(yb.x, yb.y), mkv2(yb.z, yb.w) };
                    v2f w0 = splat2(c0), w1 = splat2(c1), w2 = splat2(c2);
                    #pragma unroll
                    for (int q = 0; q < 4; q++) {
                        aA0[q] = v2fma(w0, xvA[q], aA0[q]);
                        aA1[q] = v2fma(w1, xvA[q], aA1[q]);
                        aA2[q] = v2fma(w2, xvA[q], aA2[q]);
                        aB0[q] = v2fma(w0, xvB[q], aB0[q]);
                        aB1[q] = v2fma(w1, xvB[q], aB1[q]);
                        aB2[q] = v2fma(w2, xvB[q], aB2[q]);
                    }
                }
            }
            // cross-half reduce of xg0 (off the per-step chain)
            #pragma unroll
            for (int q = 0; q < 4; q++) {
                aA0[q].x += __shfl_xor(aA0[q].x, 32, 64); aA0[q].y += __shfl_xor(aA0[q].y, 32, 64);
                aA1[q].x += __shfl_xor(aA1[q].x, 32, 64); aA1[q].y += __shfl_xor(aA1[q].y, 32, 64);
                aA2[q].x += __shfl_xor(aA2[q].x, 32, 64); aA2[q].y += __shfl_xor(aA2[q].y, 32, 64);
                aB0[q].x += __shfl_xor(aB0[q].x, 32, 64); aB0[q].y += __shfl_xor(aB0[q].y, 32, 64);
                aB1[q].x += __shfl_xor(aB1[q].x, 32, 64); aB1[q].y += __shfl_xor(aB1[q].y, 32, 64);
                aB2[q].x += __shfl_xor(aB2[q].x, 32, 64); aB2[q].y += __shfl_xor(aB2[q].y, 32, 64);
            }

            // ---- TBLK pipelined steps, two independent chains (A, B) ----
            #pragma unroll
            for (int i = 0; i < TBLK; i++) {
                // B-dots (k-half over h1 from LDS), both batches
                v2f dBA0 = mkv2(whb0, 0.f), dBA1 = mkv2(whb1, 0.f), dBA2 = mkv2(whb2, 0.f);
                v2f dBB0 = mkv2(whb0, 0.f), dBB1 = mkv2(whb1, 0.f), dBB2 = mkv2(whb2, 0.f);
                #pragma unroll
                for (int k = 0; k < 8; k++) {
                    dBA0 = v2fma(wB0[k], h1vA[k], dBA0);
                    dBA1 = v2fma(wB1[k], h1vA[k], dBA1);
                    dBA2 = v2fma(wB2[k], h1vA[k], dBA2);
                    dBB0 = v2fma(wB0[k], h1vB[k], dBB0);
                    dBB1 = v2fma(wB1[k], h1vB[k], dBB1);
                    dBB2 = v2fma(wB2[k], h1vB[k], dBB2);
                }
                float BA0 = dBA0.x + dBA0.y, BA1 = dBA1.x + dBA1.y, BA2 = dBA2.x + dBA2.y;
                float BB0 = dBB0.x + dBB0.y, BB1 = dBB1.x + dBB1.y, BB2 = dBB2.x + dBB2.y;
                float RA0 = BA0 + __shfl_xor(BA0, 32, 64);
                float RA1 = BA1 + __shfl_xor(BA1, 32, 64);
                float RA2 = BA2 + __shfl_xor(BA2, 32, 64);
                float RB0 = BB0 + __shfl_xor(BB0, 32, 64);
                float RB1 = BB1 + __shfl_xor(BB1, 32, 64);
                float RB2 = BB2 + __shfl_xor(BB2, 32, 64);
                // A-dots: full dots over transported h0, both batches
                v2f dAA0 = mkv2(selb0, 0.f), dAA1 = mkv2(selb1, 0.f), dAA2 = mkv2(selb2, 0.f);
                v2f dAB0 = mkv2(selb0, 0.f), dAB1 = mkv2(selb1, 0.f), dAB2 = mkv2(selb2, 0.f);
                #pragma unroll
                for (int k = 0; k < 16; k++) {
                    dAA0 = v2fma(sA0[k], h0vA[k], dAA0);
                    dAA1 = v2fma(sA1[k], h0vA[k], dAA1);
                    dAA2 = v2fma(sA2[k], h0vA[k], dAA2);
                    dAB0 = v2fma(sA0[k], h0vB[k], dAB0);
                    dAB1 = v2fma(sA1[k], h0vB[k], dAB1);
                    dAB2 = v2fma(sA2[k], h0vB[k], dAB2);
                }
                float AA0 = dAA0.x + dAA0.y, AA1 = dAA1.x + dAA1.y, AA2 = dAA2.x + dAA2.y;
                float AB0 = dAB0.x + dAB0.y, AB1 = dAB1.x + dAB1.y, AB2 = dAB2.x + dAB2.y;
                // gate assembly (uniform instructions, per-half operand select)
                float acA0 = aA0[i >> 1][i & 1], acA1 = aA1[i >> 1][i & 1], acA2 = aA2[i >> 1][i & 1];
                float acB0 = aB0[i >> 1][i & 1], acB1 = aB1[i >> 1][i & 1], acB2 = aB2[i >> 1][i & 1];
                float oA0   = hlf ? RA0 : acA0;
                float oA1   = hlf ? RA1 : acA1;
                float npreA = hlf ? AA2 : acA2;
                float gnA   = hlf ? RA2 : AA2;
                float rA = fsig(AA0 + oA0);
                float zA = fsig(AA1 + oA1);
                float nA = ftanh(npreA + rA * gnA);
                float hnewA = (nA + zA * (holdA - nA)) * lmul;
                float oB0   = hlf ? RB0 : acB0;
                float oB1   = hlf ? RB1 : acB1;
                float npreB = hlf ? AB2 : acB2;
                float gnB   = hlf ? RB2 : AB2;
                float rB = fsig(AB0 + oB0);
                float zB = fsig(AB1 + oB1);
                float nB = ftanh(npreB + rB * gnB);
                float hnewB = (nB + zB * (holdB - nB)) * lmul;
                holdA = hnewA; holdB = hnewB;
                lmul = 1.f;
                // h1 exchange via LDS (round trip covered by transport + A-dots)
                if (hlf) { h1A[j] = hnewA; h1B[j] = hnewB; }
                {
                    const float4* hqA = (const float4*)(h1A + k0h);
                    float4 q0 = hqA[0], q1 = hqA[1], q2 = hqA[2], q3 = hqA[3];
                    h1vA[0] = mkv2(q0.x, q0.y); h1vA[1] = mkv2(q0.z, q0.w);
                    h1vA[2] = mkv2(q1.x, q1.y); h1vA[3] = mkv2(q1.z, q1.w);
                    h1vA[4] = mkv2(q2.x, q2.y); h1vA[5] = mkv2(q2.z, q2.w);
                    h1vA[6] = mkv2(q3.x, q3.y); h1vA[7] = mkv2(q3.z, q3.w);
                    const float4* hqB = (const float4*)(h1B + k0h);
                    float4 u0 = hqB[0], u1 = hqB[1], u2 = hqB[2], u3 = hqB[3];
                    h1vB[0] = mkv2(u0.x, u0.y); h1vB[1] = mkv2(u0.z, u0.w);
                    h1vB[2] = mkv2(u1.x, u1.y); h1vB[3] = mkv2(u1.z, u1.w);
                    h1vB[4] = mkv2(u2.x, u2.y); h1vB[5] = mkv2(u2.z, u2.w);
                    h1vB[6] = mkv2(u3.x, u3.y); h1vB[7] = mkv2(u3.z, u3.w);
                }
                // h0 broadcast via v_readlane: VALU-only, no DS latency
                {
                    int hniA = __float_as_int(hnewA);
                    int hniB = __float_as_int(hnewB);
                    #pragma unroll
                    for (int k = 0; k < 16; k++) {
                        float a0e = __int_as_float(__builtin_amdgcn_readlane(hniA, 2*k));
                        float a1e = __int_as_float(__builtin_amdgcn_readlane(hniA, 2*k+1));
                        h0vA[k] = mkv2(a0e, a1e);
                        float b0e = __int_as_float(__builtin_amdgcn_readlane(hniB, 2*k));
                        float b1e = __int_as_float(__builtin_amdgcn_readlane(hniB, 2*k+1));
                        h0vB[k] = mkv2(b0e, b1e);
                    }
                }
            }
        }
    }

    // ---- epilogue: L1(LSEQ-1) for both batches (half1 results used) ----
    {
        v2f dAA0 = mkv2(selb0, 0.f), dAA1 = mkv2(selb1, 0.f), dAA2 = mkv2(selb2, 0.f);
        v2f dAB0 = mkv2(selb0, 0.f), dAB1 = mkv2(selb1, 0.f), dAB2 = mkv2(selb2, 0.f);
        #pragma unroll
        for (int k = 0; k < 16; k++) {
            dAA0 = v2fma(sA0[k], h0vA[k], dAA0);
            dAA1 = v2fma(sA1[k], h0vA[k], dAA1);
            dAA2 = v2fma(sA2[k], h0vA[k], dAA2);
            dAB0 = v2fma(sA0[k], h0vB[k], dAB0);
            dAB1 = v2fma(sA1[k], h0vB[k], dAB1);
            dAB2 = v2fma(sA2[k], h0vB[k], dAB2);
        }
        v2f dBA0 = mkv2(whb0, 0.f), dBA1 = mkv2(whb1, 0.f), dBA2 = mkv2(whb2, 0.f);
        v2f dBB0 = mkv2(whb0, 0.f), dBB1 = mkv2(whb1, 0.f), dBB2 = mkv2(whb2, 0.f);
        #pragma unroll
        for (int k = 0; k < 8; k++) {
            dBA0 = v2fma(wB0[k], h1vA[k], dBA0);
            dBA1 = v2fma(wB1[k], h1vA[k], dBA1);
            dBA2 = v2fma(wB2[k], h1vA[k], dBA2);
            dBB0 = v2fma(wB0[k], h1vB[k], dBB0);
            dBB1 = v2fma(wB1[k], h1vB[k], dBB1);
            dBB2 = v2fma(wB2[k], h1vB[k], dBB2);
        }
        float AA0 = dAA0.x + dAA0.y, AA1 = dAA1.x + dAA1.y, AA2 = dAA2.x + dAA2.y;
        float AB0 = dAB0.x + dAB0.y, AB1 = dAB1.x + dAB1.y, AB2 = dAB2.x + dAB2.y;
        float BA0 = dBA0.x + dBA0.y, BA1 = dBA1.x + dBA1.y, BA2 = dBA2.x + dBA2.y;
        float BB0 = dBB0.x + dBB0.y, BB1 = dBB1.x + dBB1.y, BB2 = dBB2.x + dBB2.y;
        float RA0 = BA0 + __shfl_xor(BA0, 32, 64);
        float RA1 = BA1 + __shfl_xor(BA1, 32, 64);
        float RA2 = BA2 + __shfl_xor(BA2, 32, 64);
        float RB0 = BB0 + __shfl_xor(BB0, 32, 64);
        float RB1 = BB1 + __shfl_xor(BB1, 32, 64);
        float RB2 = BB2 + __shfl_xor(BB2, 32, 64);
        float rA = fsig(AA0 + RA0);
        float zA = fsig(AA1 + RA1);
        float nA = ftanh(AA2 + rA * RA2);
        float hfinA = nA + zA * (holdA - nA);
        float rB = fsig(AB0 + RB0);
        float zB = fsig(AB1 + RB1);
        float nB = ftanh(AB2 + rB * RB2);
        float hfinB = nB + zB * (holdB - nB);
        if (hlf) { h1A[j] = hfinA; h1B[j] = hfinB; }
    }

    // ---- head MLP + weighted accumulation: half0 -> batch A, half1 -> B ----
    {
        const float* hsrc = hlf ? h1B : h1A;
        float s = bh1[e * NHU + j];
        const float* wr = Wh1 + ((size_t)e * NHU + j) * NH;
        #pragma unroll
        for (int d = 0; d < NH; d++) s += wr[d] * hsrc[d];
        float hid = fmaxf(s, 0.f);
        float cacc = hid * Wh2[e * NHU + j];
        #pragma unroll
        for (int off = 16; off > 0; off >>= 1) cacc += __shfl_down(cacc, off, 32);
        if (j == 0) {
            float w  = hlf ? wgtB : wgtA;
            int   bo = hlf ? bB   : bA;
            atomicAdd(out + bo, w * (cacc + bh2[e]));
        }
    }
}

extern "C" void kernel_launch(void* const* d_in, const int* in_sizes, int n_in,
                              void* d_out, int out_size, void* d_ws, size_t ws_size,
                              hipStream_t stream) {
    const float* x       = (const float*)d_in[0];
    const int*   horizon = (const int*)  d_in[1];
    const float* W_in    = (const float*)d_in[2];
    const float* b_in    = (const float*)d_in[3];
    const float* emb     = (const float*)d_in[4];
    const float* W_gate  = (const float*)d_in[5];
    const float* b_gate  = (const float*)d_in[6];
    const float* Wih0    = (const float*)d_in[7];
    const float* Whh0    = (const float*)d_in[8];
    const float* bih0    = (const float*)d_in[9];
    const float* bhh0    = (const float*)d_in[10];
    const float* Wih1    = (const float*)d_in[11];
    const float* Whh1    = (const float*)d_in[12];
    const float* bih1    = (const float*)d_in[13];
    const float* bhh1    = (const float*)d_in[14];
    const float* Wh1     = (const float*)d_in[15];
    const float* bh1     = (const float*)d_in[16];
    const float* Wh2     = (const float*)d_in[17];
    const float* bh2     = (const float*)d_in[18];
    float* out = (float*)d_out;

    // workspace layout: Cg (76800 B) | lst (4096 B) | wl (4096 B) | cnt (16 B)
    float* Cg  = (float*)d_ws;
    int*   lst = (int*)(Cg + NE * NF * G3);
    float* wl  = (float*)(lst + NE * NB);
    int*   cnt = (int*)(wl + NE * NB);

    hipMemsetAsync(d_out, 0, NB * sizeof(float), stream);
    routing_kernel<<<dim3(1), dim3(NB), 0, stream>>>(horizon, emb, W_gate, b_gate,
                                                     lst, wl, cnt);
    compute_C_kernel<<<dim3(NE), dim3(256), 0, stream>>>(Wih0, W_in, Cg);
    moe_gru_kernel<<<dim3(NE, NB / 2), dim3(64), 0, stream>>>(
        x, horizon, emb, b_in,
        Wih0, Whh0, bih0, bhh0, Wih1, Whh1, bih1, bhh1,
        Wh1, bh1, Wh2, bh2, Cg, lst, wl, cnt, out);
}

// Round 4
// 1844.271 us; speedup vs baseline: 1.2526x; 1.2526x over previous
//
#include <hip/hip_runtime.h>
#include <math.h>

#define NB   256
#define LSEQ 1800
#define NF   50
#define NE   4
#define NH   32
#define G3   96
#define ND   64
#define NHU  32
#define CHUNK 72
#define TBLK  8
#define NCHUNK (LSEQ / CHUNK)   // 25
#define NBLK   (CHUNK / TBLK)   // 9
#define WPB    8                // waves (units) per block -> 2 waves/SIMD

// dynamic LDS: CT 4800 | 8 x xs 3600 | 8 x bb 64 | 8 x h1 32  (floats)
#define SMEM_FLOATS (4800 + WPB*3600 + WPB*64 + WPB*32)
#define SMEM_BYTES  (SMEM_FLOATS * 4)   // 137472 B > 80KB -> 1 block/CU

typedef float v2f __attribute__((ext_vector_type(2)));

__device__ __forceinline__ v2f v2fma(v2f a, v2f b, v2f c) {
    return __builtin_elementwise_fma(a, b, c);
}
__device__ __forceinline__ v2f mkv2(float a, float b) { v2f t; t.x = a; t.y = b; return t; }
__device__ __forceinline__ v2f splat2(float s) { v2f t; t.x = s; t.y = s; return t; }

// ---------------------------------------------------------------------------
// Kernel 1: fold input projection into layer-0 input weights.
// Cg[e][f][g] = sum_d Wih0[e][g][d] * W_in[d][f]
// ---------------------------------------------------------------------------
__global__ void compute_C_kernel(const float* __restrict__ Wih0,
                                 const float* __restrict__ W_in,
                                 float* __restrict__ Cg) {
    int e = blockIdx.x;
    for (int idx = threadIdx.x; idx < NF * G3; idx += blockDim.x) {
        int f = idx / G3;
        int g = idx - f * G3;
        const float* wr = Wih0 + ((size_t)e * G3 + g) * ND;
        float s = 0.f;
        #pragma unroll 8
        for (int d = 0; d < ND; d++) s += wr[d] * W_in[d * NF + f];
        Cg[(size_t)e * NF * G3 + idx] = s;
    }
}

// ---------------------------------------------------------------------------
// Kernel 2: routing (one block, 256 threads; thread t = batch t).  Top-2
// gating identical to jax.lax.top_k tie-break (first max wins); appends
// (batch, weight) to each chosen expert's compacted list.  Slot order is
// irrelevant (main kernel accumulates via atomicAdd).  Proven in round 3.
// ---------------------------------------------------------------------------
__global__ void routing_kernel(const int*   __restrict__ horizon,
                               const float* __restrict__ emb,
                               const float* __restrict__ W_gate,
                               const float* __restrict__ b_gate,
                               int* __restrict__ lst, float* __restrict__ wl,
                               int* __restrict__ cnt) {
    __shared__ int scnt[NE];
    const int t = threadIdx.x;
    if (t < NE) scnt[t] = 0;
    __syncthreads();
    int hor = horizon[t];
    const float* he = emb + (size_t)hor * ND;
    float lg[NE];
    #pragma unroll
    for (int q = 0; q < NE; q++) {
        float s = b_gate[q];
        for (int d = 0; d < ND; d++) s += he[d] * W_gate[q * ND + d];
        lg[q] = s;
    }
    int i1 = 0;
    #pragma unroll
    for (int q = 1; q < NE; q++) if (lg[q] > lg[i1]) i1 = q;
    int i2 = (i1 == 0) ? 1 : 0;
    #pragma unroll
    for (int q = 0; q < NE; q++) if (q != i1 && lg[q] > lg[i2]) i2 = q;
    float ex2 = expf(lg[i2] - lg[i1]);
    float w1 = 1.f / (1.f + ex2);
    float w2 = ex2 / (1.f + ex2);
    int s1 = atomicAdd(&scnt[i1], 1);
    lst[i1 * NB + s1] = t;  wl[i1 * NB + s1] = w1;
    int s2 = atomicAdd(&scnt[i2], 1);
    lst[i2 * NB + s2] = t;  wl[i2 * NB + s2] = w2;
    __syncthreads();
    if (t < NE) cnt[t] = scnt[t];
}

// Fast transcendentals on v_exp_f32 / v_rcp_f32.
__device__ __forceinline__ float fsig(float x) {
    float e = __builtin_amdgcn_exp2f(-1.442695041f * x);
    return __builtin_amdgcn_rcpf(1.f + e);
}
__device__ __forceinline__ float ftanh(float x) {
    x = fmaxf(x, -20.f);
    float e = __builtin_amdgcn_exp2f(-2.885390082f * x);
    return (1.f - e) * __builtin_amdgcn_rcpf(1.f + e);
}

// ---------------------------------------------------------------------------
// 512-thread block = 8 waves = 8 INDEPENDENT routed units of one expert.
// Purpose: wave i -> SIMD (i&3), so 8 waves = 2 waves per SIMD.  A single
// wave only fills ~51% of its SIMD's issue cycles (round-0/3 counters); the
// co-resident second wave's instructions are hardware-interleaved into the
// first's latency bubbles (DS round trips, transcendentals, waitcnts).
// Dynamic LDS 137.5 KB forces 1 block/CU so the compiler's occupancy target
// is 2 waves/SIMD -> VGPR budget 256 (round 1 failed this: 69.5 KB static
// LDS allowed 2 blocks/CU -> target 4 waves/SIMD -> spill to 128 VGPR).
// Per-wave body is round-0's verbatim; waves share only the read-only CT.
// ---------------------------------------------------------------------------
__global__ __launch_bounds__(512, 2)
void moe_gru_kernel(const float* __restrict__ x,
                    const int*   __restrict__ horizon,
                    const float* __restrict__ emb,
                    const float* __restrict__ b_in,
                    const float* __restrict__ Wih0,
                    const float* __restrict__ Whh0,
                    const float* __restrict__ bih0,
                    const float* __restrict__ bhh0,
                    const float* __restrict__ Wih1,
                    const float* __restrict__ Whh1,
                    const float* __restrict__ bih1,
                    const float* __restrict__ bhh1,
                    const float* __restrict__ Wh1,
                    const float* __restrict__ bh1,
                    const float* __restrict__ Wh2,
                    const float* __restrict__ bh2,
                    const float* __restrict__ Cg,
                    const int*   __restrict__ lst,
                    const float* __restrict__ wl,
                    const int*   __restrict__ cnt,
                    float* __restrict__ out) {
    extern __shared__ __align__(16) float smem[];
    float* CT = smem;                                   // [f][96] shared

    const int e    = blockIdx.x;
    const int t512 = threadIdx.x;
    const int wave = t512 >> 6;
    const int tid  = t512 & 63;
    const int j    = tid & 31;
    const int hlf  = tid >> 5;
    const int k0h  = hlf << 4;

    float* xs  = smem + 4800 + wave * 3600;             // per-wave x chunk
    float* bbL = smem + 4800 + WPB * 3600 + wave * 64;  // per-wave b_in+emb
    float* h1L = smem + 4800 + WPB * 3600 + WPB * 64 + wave * 32;

    // ---- cooperative CT staging (all waves), single barrier ----
    for (int idx = t512; idx < NF * G3; idx += 512)
        CT[idx] = Cg[(size_t)e * NF * G3 + idx];
    __syncthreads();

    // ---- per-wave unit assignment; inactive waves exit after the barrier ----
    const int slot = blockIdx.y * WPB + wave;
    if (slot >= cnt[e]) return;                         // wave-uniform
    const int   b   = lst[e * NB + slot];
    const float wgt = wl[e * NB + slot];

    // ---- stage b_in + h_embed (wave-synchronous) ----
    bbL[tid] = emb[(size_t)horizon[b] * ND + tid] + b_in[tid];

    // ---- per-lane weights ----
    // selA: half0 -> Whh0 rows {j, j+32, j+64}; half1 -> Wih1 rows (full 32-k)
    v2f sA0[16], sA1[16], sA2[16];
    // wB: Whh1 rows {j, j+32, j+64}, k-half [k0h, k0h+16)
    v2f wB0[8], wB1[8], wB2[8];
    {
        const float* baseA = (hlf ? Wih1 : Whh0) + (size_t)e * G3 * NH;
        const float* rA0 = baseA + (size_t)j * NH;
        const float* rA1 = baseA + (size_t)(j + 32) * NH;
        const float* rA2 = baseA + (size_t)(j + 64) * NH;
        #pragma unroll
        for (int q4 = 0; q4 < 8; q4++) {
            float4 qa = ((const float4*)rA0)[q4];
            sA0[2*q4] = mkv2(qa.x, qa.y); sA0[2*q4+1] = mkv2(qa.z, qa.w);
            float4 qb = ((const float4*)rA1)[q4];
            sA1[2*q4] = mkv2(qb.x, qb.y); sA1[2*q4+1] = mkv2(qb.z, qb.w);
            float4 qc = ((const float4*)rA2)[q4];
            sA2[2*q4] = mkv2(qc.x, qc.y); sA2[2*q4+1] = mkv2(qc.z, qc.w);
        }
        const float* baseB = Whh1 + (size_t)e * G3 * NH;
        const float* rB0 = baseB + (size_t)j * NH + k0h;
        const float* rB1 = baseB + (size_t)(j + 32) * NH + k0h;
        const float* rB2 = baseB + (size_t)(j + 64) * NH + k0h;
        #pragma unroll
        for (int q4 = 0; q4 < 4; q4++) {
            float4 qa = ((const float4*)rB0)[q4];
            wB0[2*q4] = mkv2(qa.x, qa.y); wB0[2*q4+1] = mkv2(qa.z, qa.w);
            float4 qb = ((const float4*)rB1)[q4];
            wB1[2*q4] = mkv2(qb.x, qb.y); wB1[2*q4+1] = mkv2(qb.z, qb.w);
            float4 qc = ((const float4*)rB2)[q4];
            wB2[2*q4] = mkv2(qc.x, qc.y); wB2[2*q4+1] = mkv2(qc.z, qc.w);
        }
    }
    const float selb0 = hlf ? bih1[e*G3 + j]      : bhh0[e*G3 + j];
    const float selb1 = hlf ? bih1[e*G3 + j + 32] : bhh0[e*G3 + j + 32];
    const float selb2 = hlf ? bih1[e*G3 + j + 64] : bhh0[e*G3 + j + 64];
    const float whb0  = hlf ? 0.f : bhh1[e*G3 + j];
    const float whb1  = hlf ? 0.f : bhh1[e*G3 + j + 32];
    const float whb2  = hlf ? 0.f : bhh1[e*G3 + j + 64];

    // dreg = bih0 + Wih0 @ (b_in + h_embed), added once (half0 side of reduce)
    float dreg0, dreg1, dreg2;
    {
        float s0 = bih0[e*G3 + j], s1 = bih0[e*G3 + j + 32], s2 = bih0[e*G3 + j + 64];
        const float* w0 = Wih0 + ((size_t)e * G3 + j) * ND;
        const float* w1 = Wih0 + ((size_t)e * G3 + j + 32) * ND;
        const float* w2 = Wih0 + ((size_t)e * G3 + j + 64) * ND;
        for (int d = 0; d < ND; d++) {
            float bb = bbL[d];
            s0 += w0[d] * bb; s1 += w1[d] * bb; s2 += w2[d] * bb;
        }
        dreg0 = hlf ? 0.f : s0;
        dreg1 = hlf ? 0.f : s1;
        dreg2 = hlf ? 0.f : s2;
    }

    // ---- pipeline state ----
    v2f h0v[16], h1v[8];
    #pragma unroll
    for (int k = 0; k < 16; k++) h0v[k] = splat2(0.f);
    #pragma unroll
    for (int k = 0; k < 8; k++)  h1v[k] = splat2(0.f);
    float hold = 0.f;                    // half0: h0_j ; half1: h1_j (skewed)
    float lmul = hlf ? 0.f : 1.f;        // neutralizes the fake first L1 step
    if (tid < 32) h1L[tid] = 0.f;

    const float* xg = x + (size_t)b * LSEQ * NF;

    for (int ch = 0; ch < NCHUNK; ch++) {
        // stage x chunk (contiguous float4 global loads), transpose to [f][t]
        {
            const float4* xc4 = (const float4*)(xg + (size_t)ch * CHUNK * NF);
            for (int i4 = tid; i4 < (CHUNK * NF) / 4; i4 += 64) {
                float4 v = xc4[i4];
                int idx = i4 * 4;
                #pragma unroll
                for (int u = 0; u < 4; u++) {
                    int id = idx + u;
                    int it = (int)(((unsigned)id * 5243u) >> 18);   // id/50
                    int f  = id - it * 50;
                    float val = (u == 0) ? v.x : (u == 1) ? v.y : (u == 2) ? v.z : v.w;
                    xs[f * CHUNK + it] = val;
                }
            }
        }

        for (int blk = 0; blk < NBLK; blk++) {
            const int ib0 = blk * TBLK;
            // ---- xg0 partials for TBLK steps (f-split across halves) ----
            v2f a0[4], a1[4], a2[4];
            #pragma unroll
            for (int p = 0; p < 4; p++) {
                a0[p] = splat2(dreg0); a1[p] = splat2(dreg1); a2[p] = splat2(dreg2);
            }
            {
                const int fb = 25 * hlf;
                #pragma unroll 5
                for (int f = 0; f < 25; f++) {
                    const int fg = fb + f;
                    float c0 = CT[fg * G3 + j];
                    float c1 = CT[fg * G3 + j + 32];
                    float c2 = CT[fg * G3 + j + 64];
                    const float4* xp = (const float4*)(xs + fg * CHUNK + ib0);
                    float4 xa = xp[0], xb = xp[1];
                    v2f xv[4] = { mkv2(xa.x, xa.y), mkv2(xa.z, xa.w),
                                  mkv2(xb.x, xb.y), mkv2(xb.z, xb.w) };
                    v2f w0 = splat2(c0), w1 = splat2(c1), w2 = splat2(c2);
                    #pragma unroll
                    for (int p = 0; p < 4; p++) {
                        a0[p] = v2fma(w0, xv[p], a0[p]);
                        a1[p] = v2fma(w1, xv[p], a1[p]);
                        a2[p] = v2fma(w2, xv[p], a2[p]);
                    }
                }
            }
            // cross-half reduce of xg0 (off the per-step chain)
            #pragma unroll
            for (int p = 0; p < 4; p++) {
                a0[p].x += __shfl_xor(a0[p].x, 32, 64); a0[p].y += __shfl_xor(a0[p].y, 32, 64);
                a1[p].x += __shfl_xor(a1[p].x, 32, 64); a1[p].y += __shfl_xor(a1[p].y, 32, 64);
                a2[p].x += __shfl_xor(a2[p].x, 32, 64); a2[p].y += __shfl_xor(a2[p].y, 32, 64);
            }

            // ---- TBLK pipelined steps: L0(t) on half0 || L1(t-1) on half1 ----
            #pragma unroll
            for (int i = 0; i < TBLK; i++) {
                // B-dots (k-half over h1 from LDS), start the xor32 reduce
                v2f dB0 = mkv2(whb0, 0.f), dB1 = mkv2(whb1, 0.f), dB2 = mkv2(whb2, 0.f);
                #pragma unroll
                for (int k = 0; k < 8; k++) {
                    dB0 = v2fma(wB0[k], h1v[k], dB0);
                    dB1 = v2fma(wB1[k], h1v[k], dB1);
                    dB2 = v2fma(wB2[k], h1v[k], dB2);
                }
                float B0 = dB0.x + dB0.y, B1 = dB1.x + dB1.y, B2 = dB2.x + dB2.y;
                float R0 = B0 + __shfl_xor(B0, 32, 64);   // covered by A-dots
                float R1 = B1 + __shfl_xor(B1, 32, 64);
                float R2 = B2 + __shfl_xor(B2, 32, 64);
                // A-dots: full dots over transported h0
                v2f dA0 = mkv2(selb0, 0.f), dA1 = mkv2(selb1, 0.f), dA2 = mkv2(selb2, 0.f);
                #pragma unroll
                for (int k = 0; k < 16; k++) {
                    dA0 = v2fma(sA0[k], h0v[k], dA0);
                    dA1 = v2fma(sA1[k], h0v[k], dA1);
                    dA2 = v2fma(sA2[k], h0v[k], dA2);
                }
                float A0 = dA0.x + dA0.y, A1 = dA1.x + dA1.y, A2 = dA2.x + dA2.y;
                const float ac0 = a0[i >> 1][i & 1];
                const float ac1 = a1[i >> 1][i & 1];
                const float ac2 = a2[i >> 1][i & 1];
                // gate assembly (uniform instructions, per-half operand select)
                float o0   = hlf ? R0 : ac0;
                float o1   = hlf ? R1 : ac1;
                float npre = hlf ? A2 : ac2;
                float gn   = hlf ? R2 : A2;
                float r = fsig(A0 + o0);
                float z = fsig(A1 + o1);
                float n = ftanh(npre + r * gn);
                float hnew = (n + z * (hold - n)) * lmul;
                hold = hnew;
                lmul = 1.f;
                // h1 exchange via LDS (round trip covered by transport + A-dots)
                if (hlf) h1L[j] = hnew;
                const float4* h1q = (const float4*)(h1L + k0h);
                float4 q0 = h1q[0], q1 = h1q[1], q2 = h1q[2], q3 = h1q[3];
                h1v[0] = mkv2(q0.x, q0.y); h1v[1] = mkv2(q0.z, q0.w);
                h1v[2] = mkv2(q1.x, q1.y); h1v[3] = mkv2(q1.z, q1.w);
                h1v[4] = mkv2(q2.x, q2.y); h1v[5] = mkv2(q2.z, q2.w);
                h1v[6] = mkv2(q3.x, q3.y); h1v[7] = mkv2(q3.z, q3.w);
                // h0 broadcast via v_readlane: VALU-only, no DS latency
                {
                    int hni = __float_as_int(hnew);
                    #pragma unroll
                    for (int k = 0; k < 16; k++) {
                        float e0 = __int_as_float(__builtin_amdgcn_readlane(hni, 2*k));
                        float e1 = __int_as_float(__builtin_amdgcn_readlane(hni, 2*k+1));
                        h0v[k] = mkv2(e0, e1);
                    }
                }
            }
        }
    }

    // ---- epilogue: L1(LSEQ-1) (results used from half1 only) ----
    {
        v2f dA0 = mkv2(selb0, 0.f), dA1 = mkv2(selb1, 0.f), dA2 = mkv2(selb2, 0.f);
        #pragma unroll
        for (int k = 0; k < 16; k++) {
            dA0 = v2fma(sA0[k], h0v[k], dA0);
            dA1 = v2fma(sA1[k], h0v[k], dA1);
            dA2 = v2fma(sA2[k], h0v[k], dA2);
        }
        v2f dB0 = mkv2(whb0, 0.f), dB1 = mkv2(whb1, 0.f), dB2 = mkv2(whb2, 0.f);
        #pragma unroll
        for (int k = 0; k < 8; k++) {
            dB0 = v2fma(wB0[k], h1v[k], dB0);
            dB1 = v2fma(wB1[k], h1v[k], dB1);
            dB2 = v2fma(wB2[k], h1v[k], dB2);
        }
        float A0 = dA0.x + dA0.y, A1 = dA1.x + dA1.y, A2 = dA2.x + dA2.y;
        float B0 = dB0.x + dB0.y, B1 = dB1.x + dB1.y, B2 = dB2.x + dB2.y;
        float R0 = B0 + __shfl_xor(B0, 32, 64);
        float R1 = B1 + __shfl_xor(B1, 32, 64);
        float R2 = B2 + __shfl_xor(B2, 32, 64);
        float r = fsig(A0 + R0);
        float z = fsig(A1 + R1);
        float n = ftanh(A2 + r * R2);
        float hfin = n + z * (hold - n);
        if (hlf) h1L[j] = hfin;
    }

    // ---- head MLP + weighted accumulation ----
    if (tid < 32) {
        float s = bh1[e * NHU + tid];
        const float* wr = Wh1 + ((size_t)e * NHU + tid) * NH;
        #pragma unroll
        for (int d = 0; d < NH; d++) s += wr[d] * h1L[d];
        float hid = fmaxf(s, 0.f);
        float c = hid * Wh2[e * NHU + tid];
        #pragma unroll
        for (int off = 16; off > 0; off >>= 1) c += __shfl_down(c, off, 64);
        if (tid == 0) atomicAdd(out + b, wgt * (c + bh2[e]));
    }
}

extern "C" void kernel_launch(void* const* d_in, const int* in_sizes, int n_in,
                              void* d_out, int out_size, void* d_ws, size_t ws_size,
                              hipStream_t stream) {
    const float* x       = (const float*)d_in[0];
    const int*   horizon = (const int*)  d_in[1];
    const float* W_in    = (const float*)d_in[2];
    const float* b_in    = (const float*)d_in[3];
    const float* emb     = (const float*)d_in[4];
    const float* W_gate  = (const float*)d_in[5];
    const float* b_gate  = (const float*)d_in[6];
    const float* Wih0    = (const float*)d_in[7];
    const float* Whh0    = (const float*)d_in[8];
    const float* bih0    = (const float*)d_in[9];
    const float* bhh0    = (const float*)d_in[10];
    const float* Wih1    = (const float*)d_in[11];
    const float* Whh1    = (const float*)d_in[12];
    const float* bih1    = (const float*)d_in[13];
    const float* bhh1    = (const float*)d_in[14];
    const float* Wh1     = (const float*)d_in[15];
    const float* bh1     = (const float*)d_in[16];
    const float* Wh2     = (const float*)d_in[17];
    const float* bh2     = (const float*)d_in[18];
    float* out = (float*)d_out;

    // workspace layout: Cg (76800 B) | lst (4096 B) | wl (4096 B) | cnt (16 B)
    float* Cg  = (float*)d_ws;
    int*   lst = (int*)(Cg + NE * NF * G3);
    float* wl  = (float*)(lst + NE * NB);
    int*   cnt = (int*)(wl + NE * NB);

    // opt into >64KB dynamic LDS (idempotent; host-side, graph-capture safe)
    static bool attr_done = false;
    if (!attr_done) {
        hipFuncSetAttribute((const void*)moe_gru_kernel,
                            hipFuncAttributeMaxDynamicSharedMemorySize,
                            SMEM_BYTES);
        attr_done = true;
    }

    hipMemsetAsync(d_out, 0, NB * sizeof(float), stream);
    routing_kernel<<<dim3(1), dim3(NB), 0, stream>>>(horizon, emb, W_gate, b_gate,
                                                     lst, wl, cnt);
    compute_C_kernel<<<dim3(NE), dim3(256), 0, stream>>>(Wih0, W_in, Cg);
    moe_gru_kernel<<<dim3(NE, NB / WPB), dim3(512), SMEM_BYTES, stream>>>(
        x, horizon, emb, b_in,
        Wih0, Whh0, bih0, bhh0, Wih1, Whh1, bih1, bhh1,
        Wh1, bh1, Wh2, bh2, Cg, lst, wl, cnt, out);
}

// Round 5
// 1267.457 us; speedup vs baseline: 1.8226x; 1.4551x over previous
//
#include <hip/hip_runtime.h>
#include <math.h>

#define NB   256
#define LSEQ 1800
#define NF   50
#define NE   4
#define NH   32
#define G3   96
#define ND   64
#define NHU  32
#define CHUNK 72
#define TBLK  8
#define NCHUNK (LSEQ / CHUNK)   // 25
#define NBLK   (CHUNK / TBLK)   // 9

typedef float v2f __attribute__((ext_vector_type(2)));

__device__ __forceinline__ v2f v2fma(v2f a, v2f b, v2f c) {
    return __builtin_elementwise_fma(a, b, c);
}
__device__ __forceinline__ v2f mkv2(float a, float b) { v2f t; t.x = a; t.y = b; return t; }
__device__ __forceinline__ v2f splat2(float s) { v2f t; t.x = s; t.y = s; return t; }

// ---------------------------------------------------------------------------
// Kernel 1: fold input projection into layer-0 input weights.
// Cg[e][f][g] = sum_d Wih0[e][g][d] * W_in[d][f]   (scalar [f][96] layout:
// b32 reads at bank j -> conflict-free)
// ---------------------------------------------------------------------------
__global__ void compute_C_kernel(const float* __restrict__ Wih0,
                                 const float* __restrict__ W_in,
                                 float* __restrict__ Cg) {
    int e = blockIdx.x;
    for (int idx = threadIdx.x; idx < NF * G3; idx += blockDim.x) {
        int f = idx / G3;
        int g = idx - f * G3;
        const float* wr = Wih0 + ((size_t)e * G3 + g) * ND;
        float s = 0.f;
        #pragma unroll 8
        for (int d = 0; d < ND; d++) s += wr[d] * W_in[d * NF + f];
        Cg[(size_t)e * NF * G3 + idx] = s;
    }
}

// Fast transcendentals on v_exp_f32 / v_rcp_f32.
__device__ __forceinline__ float fsig(float x) {
    float e = __builtin_amdgcn_exp2f(-1.442695041f * x);
    return __builtin_amdgcn_rcpf(1.f + e);
}
__device__ __forceinline__ float ftanh(float x) {
    x = fmaxf(x, -20.f);
    float e = __builtin_amdgcn_exp2f(-2.885390082f * x);
    return (1.f - e) * __builtin_amdgcn_rcpf(1.f + e);
}

// ---------------------------------------------------------------------------
// One 64-thread (single-wave) block per (batch, expert); unrouted blocks exit.
// Role split with 1-step skew: half0 lane j = L0(t) row j (full 32-dots over
// h0); half1 lane j = L1(t-1) row j (xg1 full dots over h0 + gh1 k-half dots
// over h1, one xor32 reduce). h0 broadcast via v_readlane (VALU-only, no DS
// latency); h1 exchanged through LDS with its round trip covered by the
// transport + A-dots. No barriers (single wave).
// Round-5 change vs round-0: the x-chunk staging loop is software-pipelined
// (2 batches of 7 unrolled float4 loads into regs, then transpose-writes) so
// the 14 global-load latencies overlap instead of serializing (~8400 ->
// ~1100 cy/chunk of exposed stall).  Math identical.
// ---------------------------------------------------------------------------
__global__ __launch_bounds__(64, 1)
void moe_gru_kernel(const float* __restrict__ x,
                    const int*   __restrict__ horizon,
                    const float* __restrict__ emb,
                    const float* __restrict__ W_gate,
                    const float* __restrict__ b_gate,
                    const float* __restrict__ b_in,
                    const float* __restrict__ Wih0,
                    const float* __restrict__ Whh0,
                    const float* __restrict__ bih0,
                    const float* __restrict__ bhh0,
                    const float* __restrict__ Wih1,
                    const float* __restrict__ Whh1,
                    const float* __restrict__ bih1,
                    const float* __restrict__ bhh1,
                    const float* __restrict__ Wh1,
                    const float* __restrict__ bh1,
                    const float* __restrict__ Wh2,
                    const float* __restrict__ bh2,
                    const float* __restrict__ Cg,
                    float* __restrict__ out) {
    __shared__ __align__(16) float smem[4800 + 3600 + 64 + 64 + 32];
    float* CT  = smem;                  // [f][96] folded xg0 weights
    float* xs  = smem + 4800;           // [f][CHUNK] transposed x chunk
    float* heL = smem + 4800 + 3600;    // 64: h_embed
    float* bbL = heL + 64;              // 64: b_in + h_embed
    float* h1L = bbL + 64;              // 32: h1 exchange + final h1 for head

    const int bid = blockIdx.x;
    const int b   = bid >> 2;
    const int e   = bid & 3;
    const int tid = threadIdx.x;
    const int j   = tid & 31;
    const int hlf = tid >> 5;
    const int k0h = hlf << 4;

    // ---- stage h_embed / (b_in + h_embed) (wave-synchronous) ----
    {
        int hor = horizon[b];
        float he = emb[(size_t)hor * ND + tid];
        heL[tid] = he;
        bbL[tid] = he + b_in[tid];
    }

    // ---- gating (every thread computes identically) ----
    float lg[NE];
    #pragma unroll
    for (int q = 0; q < NE; q++) {
        float s = b_gate[q];
        for (int d = 0; d < ND; d++) s += heL[d] * W_gate[q * ND + d];
        lg[q] = s;
    }
    int i1 = 0;
    #pragma unroll
    for (int q = 1; q < NE; q++) if (lg[q] > lg[i1]) i1 = q;
    int i2 = (i1 == 0) ? 1 : 0;
    #pragma unroll
    for (int q = 0; q < NE; q++) if (q != i1 && lg[q] > lg[i2]) i2 = q;
    if (e != i1 && e != i2) return;          // block-uniform
    const float ex2 = expf(lg[i2] - lg[i1]);
    const float wgt = (e == i1) ? (1.f / (1.f + ex2)) : (ex2 / (1.f + ex2));

    // ---- stage folded xg0 weights into LDS ----
    for (int idx = tid; idx < NF * G3; idx += 64)
        CT[idx] = Cg[(size_t)e * NF * G3 + idx];

    // ---- per-lane weights ----
    // selA: half0 -> Whh0 rows {j, j+32, j+64}; half1 -> Wih1 rows (full 32-k)
    v2f sA0[16], sA1[16], sA2[16];
    // wB: Whh1 rows {j, j+32, j+64}, k-half [k0h, k0h+16)
    v2f wB0[8], wB1[8], wB2[8];
    {
        const float* baseA = (hlf ? Wih1 : Whh0) + (size_t)e * G3 * NH;
        const float* rA0 = baseA + (size_t)j * NH;
        const float* rA1 = baseA + (size_t)(j + 32) * NH;
        const float* rA2 = baseA + (size_t)(j + 64) * NH;
        #pragma unroll
        for (int q4 = 0; q4 < 8; q4++) {
            float4 qa = ((const float4*)rA0)[q4];
            sA0[2*q4] = mkv2(qa.x, qa.y); sA0[2*q4+1] = mkv2(qa.z, qa.w);
            float4 qb = ((const float4*)rA1)[q4];
            sA1[2*q4] = mkv2(qb.x, qb.y); sA1[2*q4+1] = mkv2(qb.z, qb.w);
            float4 qc = ((const float4*)rA2)[q4];
            sA2[2*q4] = mkv2(qc.x, qc.y); sA2[2*q4+1] = mkv2(qc.z, qc.w);
        }
        const float* baseB = Whh1 + (size_t)e * G3 * NH;
        const float* rB0 = baseB + (size_t)j * NH + k0h;
        const float* rB1 = baseB + (size_t)(j + 32) * NH + k0h;
        const float* rB2 = baseB + (size_t)(j + 64) * NH + k0h;
        #pragma unroll
        for (int q4 = 0; q4 < 4; q4++) {
            float4 qa = ((const float4*)rB0)[q4];
            wB0[2*q4] = mkv2(qa.x, qa.y); wB0[2*q4+1] = mkv2(qa.z, qa.w);
            float4 qb = ((const float4*)rB1)[q4];
            wB1[2*q4] = mkv2(qb.x, qb.y); wB1[2*q4+1] = mkv2(qb.z, qb.w);
            float4 qc = ((const float4*)rB2)[q4];
            wB2[2*q4] = mkv2(qc.x, qc.y); wB2[2*q4+1] = mkv2(qc.z, qc.w);
        }
    }
    const float selb0 = hlf ? bih1[e*G3 + j]      : bhh0[e*G3 + j];
    const float selb1 = hlf ? bih1[e*G3 + j + 32] : bhh0[e*G3 + j + 32];
    const float selb2 = hlf ? bih1[e*G3 + j + 64] : bhh0[e*G3 + j + 64];
    const float whb0  = hlf ? 0.f : bhh1[e*G3 + j];
    const float whb1  = hlf ? 0.f : bhh1[e*G3 + j + 32];
    const float whb2  = hlf ? 0.f : bhh1[e*G3 + j + 64];

    // dreg = bih0 + Wih0 @ (b_in + h_embed), added once (half0 side of reduce)
    float dreg0, dreg1, dreg2;
    {
        float s0 = bih0[e*G3 + j], s1 = bih0[e*G3 + j + 32], s2 = bih0[e*G3 + j + 64];
        const float* w0 = Wih0 + ((size_t)e * G3 + j) * ND;
        const float* w1 = Wih0 + ((size_t)e * G3 + j + 32) * ND;
        const float* w2 = Wih0 + ((size_t)e * G3 + j + 64) * ND;
        for (int d = 0; d < ND; d++) {
            float bb = bbL[d];
            s0 += w0[d] * bb; s1 += w1[d] * bb; s2 += w2[d] * bb;
        }
        dreg0 = hlf ? 0.f : s0;
        dreg1 = hlf ? 0.f : s1;
        dreg2 = hlf ? 0.f : s2;
    }

    // ---- pipeline state ----
    v2f h0v[16], h1v[8];
    #pragma unroll
    for (int k = 0; k < 16; k++) h0v[k] = splat2(0.f);
    #pragma unroll
    for (int k = 0; k < 8; k++)  h1v[k] = splat2(0.f);
    float hold = 0.f;                    // half0: h0_j ; half1: h1_j (skewed)
    float lmul = hlf ? 0.f : 1.f;        // neutralizes the fake first L1 step
    if (tid < 32) h1L[tid] = 0.f;

    const float* xg = x + (size_t)b * LSEQ * NF;

    for (int ch = 0; ch < NCHUNK; ch++) {
        // ---- stage x chunk: software-pipelined (batched loads, then
        // transpose-writes).  (CHUNK*NF)/4 = 900 float4s; u=0..13 covers
        // i4 = tid + 64u <= 895, remainder 896..899 handled by tid < 4. ----
        {
            const float4* xc4 = (const float4*)(xg + (size_t)ch * CHUNK * NF);
            float4 vb[7];
            // batch 1: issue 7 loads, then write
            #pragma unroll
            for (int u = 0; u < 7; u++) vb[u] = xc4[tid + 64 * u];
            #pragma unroll
            for (int u = 0; u < 7; u++) {
                int idx = (tid + 64 * u) * 4;
                #pragma unroll
                for (int uu = 0; uu < 4; uu++) {
                    int id = idx + uu;
                    int it = (int)(((unsigned)id * 5243u) >> 18);   // id/50
                    int f  = id - it * 50;
                    float val = (uu == 0) ? vb[u].x : (uu == 1) ? vb[u].y
                              : (uu == 2) ? vb[u].z : vb[u].w;
                    xs[f * CHUNK + it] = val;
                }
            }
            // batch 2: issue 7 loads, then write
            #pragma unroll
            for (int u = 0; u < 7; u++) vb[u] = xc4[tid + 64 * (u + 7)];
            #pragma unroll
            for (int u = 0; u < 7; u++) {
                int idx = (tid + 64 * (u + 7)) * 4;
                #pragma unroll
                for (int uu = 0; uu < 4; uu++) {
                    int id = idx + uu;
                    int it = (int)(((unsigned)id * 5243u) >> 18);   // id/50
                    int f  = id - it * 50;
                    float val = (uu == 0) ? vb[u].x : (uu == 1) ? vb[u].y
                              : (uu == 2) ? vb[u].z : vb[u].w;
                    xs[f * CHUNK + it] = val;
                }
            }
            // remainder: i4 = 896..899
            if (tid < 4) {
                float4 v = xc4[896 + tid];
                int idx = (896 + tid) * 4;
                #pragma unroll
                for (int uu = 0; uu < 4; uu++) {
                    int id = idx + uu;
                    int it = (int)(((unsigned)id * 5243u) >> 18);   // id/50
                    int f  = id - it * 50;
                    float val = (uu == 0) ? v.x : (uu == 1) ? v.y
                              : (uu == 2) ? v.z : v.w;
                    xs[f * CHUNK + it] = val;
                }
            }
        }

        for (int blk = 0; blk < NBLK; blk++) {
            const int ib0 = blk * TBLK;
            // ---- xg0 partials for TBLK steps (f-split across halves) ----
            v2f a0[4], a1[4], a2[4];
            #pragma unroll
            for (int p = 0; p < 4; p++) {
                a0[p] = splat2(dreg0); a1[p] = splat2(dreg1); a2[p] = splat2(dreg2);
            }
            {
                const int fb = 25 * hlf;
                #pragma unroll 5
                for (int f = 0; f < 25; f++) {
                    const int fg = fb + f;
                    float c0 = CT[fg * G3 + j];
                    float c1 = CT[fg * G3 + j + 32];
                    float c2 = CT[fg * G3 + j + 64];
                    const float4* xp = (const float4*)(xs + fg * CHUNK + ib0);
                    float4 xa = xp[0], xb = xp[1];
                    v2f xv[4] = { mkv2(xa.x, xa.y), mkv2(xa.z, xa.w),
                                  mkv2(xb.x, xb.y), mkv2(xb.z, xb.w) };
                    v2f w0 = splat2(c0), w1 = splat2(c1), w2 = splat2(c2);
                    #pragma unroll
                    for (int p = 0; p < 4; p++) {
                        a0[p] = v2fma(w0, xv[p], a0[p]);
                        a1[p] = v2fma(w1, xv[p], a1[p]);
                        a2[p] = v2fma(w2, xv[p], a2[p]);
                    }
                }
            }
            // cross-half reduce of xg0 (off the per-step chain)
            #pragma unroll
            for (int p = 0; p < 4; p++) {
                a0[p].x += __shfl_xor(a0[p].x, 32, 64); a0[p].y += __shfl_xor(a0[p].y, 32, 64);
                a1[p].x += __shfl_xor(a1[p].x, 32, 64); a1[p].y += __shfl_xor(a1[p].y, 32, 64);
                a2[p].x += __shfl_xor(a2[p].x, 32, 64); a2[p].y += __shfl_xor(a2[p].y, 32, 64);
            }

            // ---- TBLK pipelined steps: L0(t) on half0 || L1(t-1) on half1 ----
            #pragma unroll
            for (int i = 0; i < TBLK; i++) {
                // B-dots (k-half over h1 from LDS), start the xor32 reduce
                v2f dB0 = mkv2(whb0, 0.f), dB1 = mkv2(whb1, 0.f), dB2 = mkv2(whb2, 0.f);
                #pragma unroll
                for (int k = 0; k < 8; k++) {
                    dB0 = v2fma(wB0[k], h1v[k], dB0);
                    dB1 = v2fma(wB1[k], h1v[k], dB1);
                    dB2 = v2fma(wB2[k], h1v[k], dB2);
                }
                float B0 = dB0.x + dB0.y, B1 = dB1.x + dB1.y, B2 = dB2.x + dB2.y;
                float R0 = B0 + __shfl_xor(B0, 32, 64);   // covered by A-dots
                float R1 = B1 + __shfl_xor(B1, 32, 64);
                float R2 = B2 + __shfl_xor(B2, 32, 64);
                // A-dots: full dots over transported h0
                v2f dA0 = mkv2(selb0, 0.f), dA1 = mkv2(selb1, 0.f), dA2 = mkv2(selb2, 0.f);
                #pragma unroll
                for (int k = 0; k < 16; k++) {
                    dA0 = v2fma(sA0[k], h0v[k], dA0);
                    dA1 = v2fma(sA1[k], h0v[k], dA1);
                    dA2 = v2fma(sA2[k], h0v[k], dA2);
                }
                float A0 = dA0.x + dA0.y, A1 = dA1.x + dA1.y, A2 = dA2.x + dA2.y;
                const float ac0 = a0[i >> 1][i & 1];
                const float ac1 = a1[i >> 1][i & 1];
                const float ac2 = a2[i >> 1][i & 1];
                // gate assembly (uniform instructions, per-half operand select)
                float o0   = hlf ? R0 : ac0;
                float o1   = hlf ? R1 : ac1;
                float npre = hlf ? A2 : ac2;
                float gn   = hlf ? R2 : A2;
                float r = fsig(A0 + o0);
                float z = fsig(A1 + o1);
                float n = ftanh(npre + r * gn);
                float hnew = (n + z * (hold - n)) * lmul;
                hold = hnew;
                lmul = 1.f;
                // h1 exchange via LDS (round trip covered by transport + A-dots)
                if (hlf) h1L[j] = hnew;
                const float4* h1q = (const float4*)(h1L + k0h);
                float4 q0 = h1q[0], q1 = h1q[1], q2 = h1q[2], q3 = h1q[3];
                h1v[0] = mkv2(q0.x, q0.y); h1v[1] = mkv2(q0.z, q0.w);
                h1v[2] = mkv2(q1.x, q1.y); h1v[3] = mkv2(q1.z, q1.w);
                h1v[4] = mkv2(q2.x, q2.y); h1v[5] = mkv2(q2.z, q2.w);
                h1v[6] = mkv2(q3.x, q3.y); h1v[7] = mkv2(q3.z, q3.w);
                // h0 broadcast via v_readlane: VALU-only, no DS latency
                {
                    int hni = __float_as_int(hnew);
                    #pragma unroll
                    for (int k = 0; k < 16; k++) {
                        float e0 = __int_as_float(__builtin_amdgcn_readlane(hni, 2*k));
                        float e1 = __int_as_float(__builtin_amdgcn_readlane(hni, 2*k+1));
                        h0v[k] = mkv2(e0, e1);
                    }
                }
            }
        }
    }

    // ---- epilogue: L1(LSEQ-1) (results used from half1 only) ----
    {
        v2f dA0 = mkv2(selb0, 0.f), dA1 = mkv2(selb1, 0.f), dA2 = mkv2(selb2, 0.f);
        #pragma unroll
        for (int k = 0; k < 16; k++) {
            dA0 = v2fma(sA0[k], h0v[k], dA0);
            dA1 = v2fma(sA1[k], h0v[k], dA1);
            dA2 = v2fma(sA2[k], h0v[k], dA2);
        }
        v2f dB0 = mkv2(whb0, 0.f), dB1 = mkv2(whb1, 0.f), dB2 = mkv2(whb2, 0.f);
        #pragma unroll
        for (int k = 0; k < 8; k++) {
            dB0 = v2fma(wB0[k], h1v[k], dB0);
            dB1 = v2fma(wB1[k], h1v[k], dB1);
            dB2 = v2fma(wB2[k], h1v[k], dB2);
        }
        float A0 = dA0.x + dA0.y, A1 = dA1.x + dA1.y, A2 = dA2.x + dA2.y;
        float B0 = dB0.x + dB0.y, B1 = dB1.x + dB1.y, B2 = dB2.x + dB2.y;
        float R0 = B0 + __shfl_xor(B0, 32, 64);
        float R1 = B1 + __shfl_xor(B1, 32, 64);
        float R2 = B2 + __shfl_xor(B2, 32, 64);
        float r = fsig(A0 + R0);
        float z = fsig(A1 + R1);
        float n = ftanh(A2 + r * R2);
        float hfin = n + z * (hold - n);
        if (hlf) h1L[j] = hfin;
    }

    // ---- head MLP + weighted accumulation ----
    if (tid < 32) {
        float s = bh1[e * NHU + tid];
        const float* wr = Wh1 + ((size_t)e * NHU + tid) * NH;
        #pragma unroll
        for (int d = 0; d < NH; d++) s += wr[d] * h1L[d];
        float hid = fmaxf(s, 0.f);
        float c = hid * Wh2[e * NHU + tid];
        #pragma unroll
        for (int off = 16; off > 0; off >>= 1) c += __shfl_down(c, off, 64);
        if (tid == 0) atomicAdd(out + b, wgt * (c + bh2[e]));
    }
}

extern "C" void kernel_launch(void* const* d_in, const int* in_sizes, int n_in,
                              void* d_out, int out_size, void* d_ws, size_t ws_size,
                              hipStream_t stream) {
    const float* x       = (const float*)d_in[0];
    const int*   horizon = (const int*)  d_in[1];
    const float* W_in    = (const float*)d_in[2];
    const float* b_in    = (const float*)d_in[3];
    const float* emb     = (const float*)d_in[4];
    const float* W_gate  = (const float*)d_in[5];
    const float* b_gate  = (const float*)d_in[6];
    const float* Wih0    = (const float*)d_in[7];
    const float* Whh0    = (const float*)d_in[8];
    const float* bih0    = (const float*)d_in[9];
    const float* bhh0    = (const float*)d_in[10];
    const float* Wih1    = (const float*)d_in[11];
    const float* Whh1    = (const float*)d_in[12];
    const float* bih1    = (const float*)d_in[13];
    const float* bhh1    = (const float*)d_in[14];
    const float* Wh1     = (const float*)d_in[15];
    const float* bh1     = (const float*)d_in[16];
    const float* Wh2     = (const float*)d_in[17];
    const float* bh2     = (const float*)d_in[18];
    float* out = (float*)d_out;
    float* Cg  = (float*)d_ws;   // NE*NF*G3 floats = 76.8 KB

    hipMemsetAsync(d_out, 0, NB * sizeof(float), stream);
    compute_C_kernel<<<dim3(NE), dim3(256), 0, stream>>>(Wih0, W_in, Cg);
    moe_gru_kernel<<<dim3(NB * NE), dim3(64), 0, stream>>>(
        x, horizon, emb, W_gate, b_gate, b_in,
        Wih0, Whh0, bih0, bhh0, Wih1, Whh1, bih1, bhh1,
        Wh1, bh1, Wh2, bh2, Cg, out);
}